// Round 1
// baseline (3441.171 us; speedup 1.0000x reference)
//
#include <hip/hip_runtime.h>
#include <stdint.h>

#define T_STEPS 512

typedef __bf16 bf16x8v __attribute__((ext_vector_type(8)));
typedef float f32x4 __attribute__((ext_vector_type(4)));
typedef unsigned short u16x8 __attribute__((ext_vector_type(8)));

__device__ __forceinline__ unsigned short f2bf(float f) {
    unsigned u = __float_as_uint(f);
    return (unsigned short)((u + 0x7fffu + ((u >> 16) & 1u)) >> 16);
}

typedef __attribute__((address_space(1))) void as1_void;
typedef __attribute__((address_space(3))) void as3_void;

__device__ __forceinline__ void async16(const void* g, void* l) {
    __builtin_amdgcn_global_load_lds((as1_void*)(void*)g, (as3_void*)l, 16, 0, 0);
}
__device__ __forceinline__ void async4(const void* g, void* l) {
    __builtin_amdgcn_global_load_lds((as1_void*)(void*)g, (as3_void*)l, 4, 0, 0);
}

// ---------------- rowdot: out[r] = M[r, coff:coff+2048] . [h0|c0] (+b1+b2) ----
__global__ void k_rowdot(const float* __restrict__ M, int rs, int coff,
                         const float* __restrict__ h0, const float* __restrict__ c0,
                         const float* __restrict__ b1, const float* __restrict__ b2,
                         float* __restrict__ out, int nrows) {
    int wave = threadIdx.x >> 6, lane = threadIdx.x & 63;
    int r = blockIdx.x * 4 + wave;
    if (r >= nrows) return;
    const float* row = M + (long)r * rs + coff;
    float acc = 0.f;
#pragma unroll
    for (int it = 0; it < 8; ++it) {
        int k = it * 256 + lane * 4;
        float4 w = *(const float4*)(row + k);
        const float4* xp = (k < 1024) ? (const float4*)(h0 + k)
                                      : (const float4*)(c0 + (k - 1024));
        float4 x = *xp;
        acc += w.x * x.x + w.y * x.y + w.z * x.z + w.w * x.w;
    }
#pragma unroll
    for (int off = 32; off; off >>= 1) acc += __shfl_xor(acc, off, 64);
    if (lane == 0) {
        if (b1) acc += b1[r];
        if (b2) acc += b2[r];
        out[r] = acc;
    }
}

// ---------------- embedding gather -> bf16 into U[:,1024:1536] ----------------
__global__ void k_embs(const int* __restrict__ ids, const float* __restrict__ emb,
                       unsigned short* __restrict__ U) {
    int t = blockIdx.x, j = threadIdx.x;
    int id = ids[(t + T_STEPS - 1) & (T_STEPS - 1)];
    float2 v = *(const float2*)(emb + (long)id * 512 + j * 2);
    ushort2 s;
    s.x = f2bf(v.x); s.y = f2bf(v.y);
    *(ushort2*)(U + (long)t * 1536 + 1024 + j * 2) = s;
}

// ---------------- W_ih[:, :512] -> bf16 [4096][512] ---------------------------
__global__ void k_convW(const float* __restrict__ Wih, unsigned short* __restrict__ Wb) {
    int i = blockIdx.x * 256 + threadIdx.x;   // 524288 float4s
    int r = i >> 7, c4 = i & 127;
    float4 f = *(const float4*)(Wih + (long)r * 2560 + c4 * 4);
    ushort4 s;
    s.x = f2bf(f.x); s.y = f2bf(f.y); s.z = f2bf(f.z); s.w = f2bf(f.w);
    *(ushort4*)(Wb + (long)r * 512 + c4 * 4) = s;
}

// ---------------- [X|Y] -> bf16 V[32000][1536] --------------------------------
__global__ void k_convXY(const float* __restrict__ X, const float* __restrict__ Y,
                         unsigned short* __restrict__ V) {
    long i = (long)blockIdx.x * 256 + threadIdx.x;
    const long NX = (long)32000 * 256;
    if (i < NX) {
        long v = i >> 8; int c4 = (int)(i & 255);
        float4 f = *(const float4*)(X + v * 1024 + c4 * 4);
        ushort4 s;
        s.x = f2bf(f.x); s.y = f2bf(f.y); s.z = f2bf(f.z); s.w = f2bf(f.w);
        *(ushort4*)(V + v * 1536 + c4 * 4) = s;
    } else {
        i -= NX;
        long v = i >> 7; int c4 = (int)(i & 127);
        float4 f = *(const float4*)(Y + v * 512 + c4 * 4);
        ushort4 s;
        s.x = f2bf(f.x); s.y = f2bf(f.y); s.z = f2bf(f.z); s.w = f2bf(f.w);
        *(ushort4*)(V + v * 1536 + 1024 + c4 * 4) = s;
    }
}

// ---------------- m97-style bf16 MFMA GEMM, C = A·B^T + bias ------------------
__global__ __launch_bounds__(256) void k_gemm_bt(
    const unsigned short* __restrict__ A, int lda,
    const unsigned short* __restrict__ B, int ldb,
    float* __restrict__ C, int ldc,
    const float* __restrict__ bias, int K) {
    __shared__ __align__(16) unsigned short As[128 * 32];
    __shared__ __align__(16) unsigned short Bs[128 * 32];
    const int tid = threadIdx.x;
    const long m0 = (long)blockIdx.y * 128, n0 = (long)blockIdx.x * 128;
    const int wave = tid >> 6, lane = tid & 63;
    const int wm = (wave >> 1) * 64, wn = (wave & 1) * 64;
    const int lm = lane & 15, lk = (lane >> 4) * 8;
    const int r0 = tid >> 2, r1 = (tid + 256) >> 2, kc = (tid & 3) * 8;
    const unsigned short* Ab = A + m0 * lda;
    const unsigned short* Bb = B + n0 * ldb;

    f32x4 acc[4][4];
#pragma unroll
    for (int i = 0; i < 4; ++i)
#pragma unroll
        for (int j = 0; j < 4; ++j) {
            f32x4 z = {0.f, 0.f, 0.f, 0.f};
            acc[i][j] = z;
        }

    for (int k0 = 0; k0 < K; k0 += 32) {
        async16(Ab + (long)r0 * lda + k0 + kc, &As[tid * 8]);
        async16(Ab + (long)r1 * lda + k0 + kc, &As[(tid + 256) * 8]);
        async16(Bb + (long)r0 * ldb + k0 + kc, &Bs[tid * 8]);
        async16(Bb + (long)r1 * ldb + k0 + kc, &Bs[(tid + 256) * 8]);
        __syncthreads();
        bf16x8v af[4], bfr[4];
#pragma unroll
        for (int t = 0; t < 4; ++t) af[t] = *(const bf16x8v*)&As[(wm + t * 16 + lm) * 32 + lk];
#pragma unroll
        for (int t = 0; t < 4; ++t) bfr[t] = *(const bf16x8v*)&Bs[(wn + t * 16 + lm) * 32 + lk];
#pragma unroll
        for (int i = 0; i < 4; ++i)
#pragma unroll
            for (int j = 0; j < 4; ++j)
                acc[i][j] = __builtin_amdgcn_mfma_f32_16x16x32_bf16(af[i], bfr[j], acc[i][j], 0, 0, 0);
        __syncthreads();
    }
    const int quad = lane >> 4;
#pragma unroll
    for (int j = 0; j < 4; ++j) {
        long col = n0 + wn + j * 16 + lm;
        float bv = bias ? bias[col] : 0.0f;
#pragma unroll
        for (int i = 0; i < 4; ++i)
#pragma unroll
            for (int rg = 0; rg < 4; ++rg) {
                long row = m0 + wm + i * 16 + quad * 4 + rg;
                C[row * (long)ldc + col] = acc[i][j][rg] + bv;
            }
    }
}

// ---------------- persistent LSTM scan, counter-gated exchange ----------------
// 256 blocks, block b owns cells [4b,4b+4) (16 gate rows). W_hh slice lives in
// 64 f32 VGPRs per thread. Exchange protocol (anti-congestion redesign):
//   producer (lane 0): 2x relaxed 8B tagged stores (2xfp16|step tag),
//                      s_waitcnt vmcnt(0), relaxed fetch_add on global counter.
//   consumer: ONE thread polls counter >= 256*t (1 line, ~256 reqs/round
//             chip-wide instead of ~131K tagged polls/step), barrier, then each
//             thread does one dual tagged load (guaranteed hit; tag loop kept
//             as a correctness belt - worst case degenerates to old behavior).
// Pointwise runs on 16 lanes of wave 0 (sigma-form tanh), not 2 threads.
__global__ __launch_bounds__(256, 1) void k_scan(
    const float* __restrict__ Whh, const float* __restrict__ gx,
    const float* __restrict__ h0, const float* __restrict__ c0,
    unsigned long long* __restrict__ hx, unsigned* __restrict__ cnt,
    unsigned short* __restrict__ U) {
    __shared__ __align__(16) float hs[1024];
    __shared__ __align__(16) float gxb[32 * 16];
    __shared__ float gv[16];
    const int b = blockIdx.x, tid = threadIdx.x;
    const int lr = tid >> 4, seg = tid & 15;

    // one-time: this thread's fixed W_hh slice -> 64 f32 registers.
    // row lr -> global gate row (lr>>2)*1024 + b*4 + (lr&3); cols u*128+seg*8+0..7
    const float* wrow = Whh + (long)((lr >> 2) * 1024 + b * 4 + (lr & 3)) * 1024;
    f32x4 wv[16];
#pragma unroll
    for (int u = 0; u < 8; ++u) {
        wv[2 * u]     = *(const f32x4*)(wrow + u * 128 + seg * 8);
        wv[2 * u + 1] = *(const f32x4*)(wrow + u * 128 + seg * 8 + 4);
    }
    // cell state: lane j (j<4) of wave 0 holds cell j (local idx)
    float cst = (tid < 4) ? c0[b * 4 + tid] : 0.f;

    for (int t = 0; t < T_STEPS; ++t) {
        if ((t & 31) == 0) {   // pre-stage gates_x for steps t..t+31
            __syncthreads();   // protect gxb vs previous step's pointwise reads
            int c = tid;
            async4(gx + (long)(t + (c >> 4)) * 4096 + ((c & 15) >> 2) * 1024 + b * 4 + (c & 3), &gxb[c]);
            c = tid + 256;
            async4(gx + (long)(t + (c >> 4)) * 4096 + ((c & 15) >> 2) * 1024 + b * 4 + (c & 3), &gxb[c]);
        }
        if (t == 0) {
            float4 hv = *(const float4*)(h0 + tid * 4);
            *(float4*)&hs[tid * 4] = hv;
        } else {
            if (tid == 0) {   // single-thread gate on the step counter
                const unsigned need = (unsigned)t << 8;   // 256*t
                while (__hip_atomic_load(cnt, __ATOMIC_RELAXED, __HIP_MEMORY_SCOPE_AGENT) < need) {
                    __builtin_amdgcn_s_sleep(1);
                }
            }
            __syncthreads();
            // all producers done -> both loads issue concurrently, expect 1 pass
            const unsigned long long* src = hx + (long)(t & 1) * 512 + tid * 2;
            unsigned long long w0, w1;
            const unsigned tt = (unsigned)t;
            do {
                w0 = __hip_atomic_load(src,     __ATOMIC_RELAXED, __HIP_MEMORY_SCOPE_AGENT);
                w1 = __hip_atomic_load(src + 1, __ATOMIC_RELAXED, __HIP_MEMORY_SCOPE_AGENT);
            } while ((((unsigned)(w0 >> 32) ^ tt) | ((unsigned)(w1 >> 32) ^ tt)) != 0u);
            union { unsigned u; _Float16 h[2]; } p0, p1;
            p0.u = (unsigned)w0; p1.u = (unsigned)w1;
            hs[tid * 4 + 0] = (float)p0.h[0];
            hs[tid * 4 + 1] = (float)p0.h[1];
            hs[tid * 4 + 2] = (float)p1.h[0];
            hs[tid * 4 + 3] = (float)p1.h[1];
        }
        __syncthreads();   // hs ready; also drains gxb async loads

        // matvec: thread (lr,seg) accumulates its 64-col slice of row lr
        float acc = 0.f;
#pragma unroll
        for (int u = 0; u < 8; ++u) {
            const f32x4 ha = *(const f32x4*)&hs[u * 128 + seg * 8];
            const f32x4 hb = *(const f32x4*)&hs[u * 128 + seg * 8 + 4];
            const f32x4 wa = wv[2 * u], wb = wv[2 * u + 1];
            acc += wa[0] * ha[0] + wa[1] * ha[1] + wa[2] * ha[2] + wa[3] * ha[3]
                 + wb[0] * hb[0] + wb[1] * hb[1] + wb[2] * hb[2] + wb[3] * hb[3];
        }
#pragma unroll
        for (int off = 1; off < 16; off <<= 1) acc += __shfl_xor(acc, off, 64);
        if (seg == 0) gv[lr] = acc;
        __syncthreads();

        // pointwise: 16 lanes of wave 0, one gate each (lane = gate*4 + cell)
        if (tid < 16) {
            const int sl = (t & 31) * 16;
            float x = gv[tid] + gxb[sl + tid];
            const bool isg = (tid & 12) == 8;          // lanes 8..11 = g-gate
            float y = isg ? (x + x) : x;
            float s = 1.f / (1.f + expf(-y));          // sigma(y)
            float v = isg ? (s + s - 1.f) : s;         // tanh(x) = 2*sigma(2x)-1
            const int cell = tid & 3;
            float iv = __shfl(v, cell,      64);
            float fv = __shfl(v, cell + 4,  64);
            float gg = __shfl(v, cell + 8,  64);
            float ov = __shfl(v, cell + 12, 64);
            float hn = 0.f;
            if (tid < 4) {   // lanes 0..3: one cell each
                float cn = fv * cst + iv * gg;
                cst = cn;
                hn = ov * tanhf(cn);
                U[(long)t * 1536 + b * 4 + tid] = f2bf(hn);
            }
            // gather h0..h3 to lane 0 (all 16 lanes execute; sources active)
            float h1 = __shfl(hn, 1, 64);
            float h2 = __shfl(hn, 2, 64);
            float h3 = __shfl(hn, 3, 64);
            if (tid == 0) {
                union { unsigned u; _Float16 h[2]; } pa, pb;
                pa.h[0] = (_Float16)hn; pa.h[1] = (_Float16)h1;
                pb.h[0] = (_Float16)h2; pb.h[1] = (_Float16)h3;
                const unsigned long long tg = (unsigned long long)(unsigned)(t + 1) << 32;
                unsigned long long* dst = hx + (long)((t + 1) & 1) * 512 + b * 2;
                __hip_atomic_store(dst,     (unsigned long long)pa.u | tg,
                                   __ATOMIC_RELAXED, __HIP_MEMORY_SCOPE_AGENT);
                __hip_atomic_store(dst + 1, (unsigned long long)pb.u | tg,
                                   __ATOMIC_RELAXED, __HIP_MEMORY_SCOPE_AGENT);
                // order: tagged data stores complete at coherence point, THEN add.
                // manual fence (not ATOMIC_RELEASE) to avoid any L2-writeback op.
                asm volatile("s_waitcnt vmcnt(0)" ::: "memory");
                __hip_atomic_fetch_add(cnt, 1u, __ATOMIC_RELAXED, __HIP_MEMORY_SCOPE_AGENT);
            }
        }
        // no trailing barrier: hs/gxb overwrites are fenced by the gate barrier
        // and staging barrier of the next iteration (all threads passed the
        // post-matvec __syncthreads before any buffer is rewritten).
    }
}

extern "C" void kernel_launch(void* const* d_in, const int* in_sizes, int n_in,
                              void* d_out, int out_size, void* d_ws, size_t ws_size,
                              hipStream_t stream) {
    const float* h0  = (const float*)d_in[0];
    const float* c0  = (const float*)d_in[1];
    const int*   ids = (const int*)d_in[2];
    const float* emb = (const float*)d_in[3];
    const float* Wih = (const float*)d_in[4];
    const float* Whh = (const float*)d_in[5];
    const float* bih = (const float*)d_in[6];
    const float* bhh = (const float*)d_in[7];
    const float* X   = (const float*)d_in[8];
    const float* Y   = (const float*)d_in[9];
    const float* Z   = (const float*)d_in[10];
    float* out = (float*)d_out;

    char* ws = (char*)d_ws;
    size_t off = 0;
    auto take = [&](size_t bytes) -> char* {
        char* p = ws + off;
        off = (off + bytes + 511) & ~(size_t)511;
        return p;
    };
    unsigned long long* hx = (unsigned long long*)take(2 * 512 * 8 + 256);
    unsigned* cnt        = (unsigned*)((char*)hx + 2 * 512 * 8);  // own cache line
    float* wf            = (float*)take(4096 * 4);
    float* zf            = (float*)take(32000 * 4);
    unsigned short* U    = (unsigned short*)take((size_t)512 * 1536 * 2);
    unsigned short* Wihb = (unsigned short*)take((size_t)4096 * 512 * 2);
    float* gatesx        = (float*)take((size_t)512 * 4096 * 4);
    unsigned short* Vbf  = (unsigned short*)take((size_t)32000 * 1536 * 2);
    (void)in_sizes; (void)n_in; (void)out_size; (void)ws_size;

    hipMemsetAsync(hx, 0, 2 * 512 * 8 + 256, stream);   // clear tags + counter
    // wf = W_ih[:,512:]@[h0|c0] + b_ih + b_hh ; zf = Z@[h0|c0]
    k_rowdot<<<1024, 256, 0, stream>>>(Wih, 2560, 512, h0, c0, bih, bhh, wf, 4096);
    k_rowdot<<<8000, 256, 0, stream>>>(Z, 2048, 0, h0, c0, nullptr, nullptr, zf, 32000);
    k_embs<<<512, 256, 0, stream>>>(ids, emb, U);
    k_convW<<<2048, 256, 0, stream>>>(Wih, Wihb);
    // gates_x[t][r] = emb_bf[t]·Wihb[r] + wf[r]
    k_gemm_bt<<<dim3(32, 4), 256, 0, stream>>>(U + 1024, 1536, Wihb, 512, gatesx, 4096, wf, 512);
    k_convXY<<<48000, 256, 0, stream>>>(X, Y, Vbf);
    k_scan<<<256, 256, 0, stream>>>(Whh, gatesx, h0, c0, hx, cnt, U);
    // scores = [hs|emb]·[X|Y]^T + zf
    k_gemm_bt<<<dim3(250, 4), 256, 0, stream>>>(U, 1536, Vbf, 1536, out, 32000, zf, 1536);
}

// Round 2
// 1873.612 us; speedup vs baseline: 1.8367x; 1.8367x over previous
//
#include <hip/hip_runtime.h>
#include <stdint.h>

#define T_STEPS 512

typedef __bf16 bf16x8v __attribute__((ext_vector_type(8)));
typedef float f32x4 __attribute__((ext_vector_type(4)));
typedef unsigned short u16x8 __attribute__((ext_vector_type(8)));

__device__ __forceinline__ unsigned short f2bf(float f) {
    unsigned u = __float_as_uint(f);
    return (unsigned short)((u + 0x7fffu + ((u >> 16) & 1u)) >> 16);
}

typedef __attribute__((address_space(1))) void as1_void;
typedef __attribute__((address_space(3))) void as3_void;

__device__ __forceinline__ void async16(const void* g, void* l) {
    __builtin_amdgcn_global_load_lds((as1_void*)(void*)g, (as3_void*)l, 16, 0, 0);
}
__device__ __forceinline__ void async4(const void* g, void* l) {
    __builtin_amdgcn_global_load_lds((as1_void*)(void*)g, (as3_void*)l, 4, 0, 0);
}

// ---------------- rowdot: out[r] = M[r, coff:coff+2048] . [h0|c0] (+b1+b2) ----
__global__ void k_rowdot(const float* __restrict__ M, int rs, int coff,
                         const float* __restrict__ h0, const float* __restrict__ c0,
                         const float* __restrict__ b1, const float* __restrict__ b2,
                         float* __restrict__ out, int nrows) {
    int wave = threadIdx.x >> 6, lane = threadIdx.x & 63;
    int r = blockIdx.x * 4 + wave;
    if (r >= nrows) return;
    const float* row = M + (long)r * rs + coff;
    float acc = 0.f;
#pragma unroll
    for (int it = 0; it < 8; ++it) {
        int k = it * 256 + lane * 4;
        float4 w = *(const float4*)(row + k);
        const float4* xp = (k < 1024) ? (const float4*)(h0 + k)
                                      : (const float4*)(c0 + (k - 1024));
        float4 x = *xp;
        acc += w.x * x.x + w.y * x.y + w.z * x.z + w.w * x.w;
    }
#pragma unroll
    for (int off = 32; off; off >>= 1) acc += __shfl_xor(acc, off, 64);
    if (lane == 0) {
        if (b1) acc += b1[r];
        if (b2) acc += b2[r];
        out[r] = acc;
    }
}

// ---------------- embedding gather -> bf16 into U[:,1024:1536] ----------------
__global__ void k_embs(const int* __restrict__ ids, const float* __restrict__ emb,
                       unsigned short* __restrict__ U) {
    int t = blockIdx.x, j = threadIdx.x;
    int id = ids[(t + T_STEPS - 1) & (T_STEPS - 1)];
    float2 v = *(const float2*)(emb + (long)id * 512 + j * 2);
    ushort2 s;
    s.x = f2bf(v.x); s.y = f2bf(v.y);
    *(ushort2*)(U + (long)t * 1536 + 1024 + j * 2) = s;
}

// ---------------- W_ih[:, :512] -> bf16 [4096][512] ---------------------------
__global__ void k_convW(const float* __restrict__ Wih, unsigned short* __restrict__ Wb) {
    int i = blockIdx.x * 256 + threadIdx.x;   // 524288 float4s
    int r = i >> 7, c4 = i & 127;
    float4 f = *(const float4*)(Wih + (long)r * 2560 + c4 * 4);
    ushort4 s;
    s.x = f2bf(f.x); s.y = f2bf(f.y); s.z = f2bf(f.z); s.w = f2bf(f.w);
    *(ushort4*)(Wb + (long)r * 512 + c4 * 4) = s;
}

// ---------------- [X|Y] -> bf16 V[32000][1536] --------------------------------
__global__ void k_convXY(const float* __restrict__ X, const float* __restrict__ Y,
                         unsigned short* __restrict__ V) {
    long i = (long)blockIdx.x * 256 + threadIdx.x;
    const long NX = (long)32000 * 256;
    if (i < NX) {
        long v = i >> 8; int c4 = (int)(i & 255);
        float4 f = *(const float4*)(X + v * 1024 + c4 * 4);
        ushort4 s;
        s.x = f2bf(f.x); s.y = f2bf(f.y); s.z = f2bf(f.z); s.w = f2bf(f.w);
        *(ushort4*)(V + v * 1536 + c4 * 4) = s;
    } else {
        i -= NX;
        long v = i >> 7; int c4 = (int)(i & 127);
        float4 f = *(const float4*)(Y + v * 512 + c4 * 4);
        ushort4 s;
        s.x = f2bf(f.x); s.y = f2bf(f.y); s.z = f2bf(f.z); s.w = f2bf(f.w);
        *(ushort4*)(V + v * 1536 + 1024 + c4 * 4) = s;
    }
}

// ---------------- m97-style bf16 MFMA GEMM, C = A·B^T + bias ------------------
__global__ __launch_bounds__(256) void k_gemm_bt(
    const unsigned short* __restrict__ A, int lda,
    const unsigned short* __restrict__ B, int ldb,
    float* __restrict__ C, int ldc,
    const float* __restrict__ bias, int K) {
    __shared__ __align__(16) unsigned short As[128 * 32];
    __shared__ __align__(16) unsigned short Bs[128 * 32];
    const int tid = threadIdx.x;
    const long m0 = (long)blockIdx.y * 128, n0 = (long)blockIdx.x * 128;
    const int wave = tid >> 6, lane = tid & 63;
    const int wm = (wave >> 1) * 64, wn = (wave & 1) * 64;
    const int lm = lane & 15, lk = (lane >> 4) * 8;
    const int r0 = tid >> 2, r1 = (tid + 256) >> 2, kc = (tid & 3) * 8;
    const unsigned short* Ab = A + m0 * lda;
    const unsigned short* Bb = B + n0 * ldb;

    f32x4 acc[4][4];
#pragma unroll
    for (int i = 0; i < 4; ++i)
#pragma unroll
        for (int j = 0; j < 4; ++j) {
            f32x4 z = {0.f, 0.f, 0.f, 0.f};
            acc[i][j] = z;
        }

    for (int k0 = 0; k0 < K; k0 += 32) {
        async16(Ab + (long)r0 * lda + k0 + kc, &As[tid * 8]);
        async16(Ab + (long)r1 * lda + k0 + kc, &As[(tid + 256) * 8]);
        async16(Bb + (long)r0 * ldb + k0 + kc, &Bs[tid * 8]);
        async16(Bb + (long)r1 * ldb + k0 + kc, &Bs[(tid + 256) * 8]);
        __syncthreads();
        bf16x8v af[4], bfr[4];
#pragma unroll
        for (int t = 0; t < 4; ++t) af[t] = *(const bf16x8v*)&As[(wm + t * 16 + lm) * 32 + lk];
#pragma unroll
        for (int t = 0; t < 4; ++t) bfr[t] = *(const bf16x8v*)&Bs[(wn + t * 16 + lm) * 32 + lk];
#pragma unroll
        for (int i = 0; i < 4; ++i)
#pragma unroll
            for (int j = 0; j < 4; ++j)
                acc[i][j] = __builtin_amdgcn_mfma_f32_16x16x32_bf16(af[i], bfr[j], acc[i][j], 0, 0, 0);
        __syncthreads();
    }
    const int quad = lane >> 4;
#pragma unroll
    for (int j = 0; j < 4; ++j) {
        long col = n0 + wn + j * 16 + lm;
        float bv = bias ? bias[col] : 0.0f;
#pragma unroll
        for (int i = 0; i < 4; ++i)
#pragma unroll
            for (int rg = 0; rg < 4; ++rg) {
                long row = m0 + wm + i * 16 + quad * 4 + rg;
                C[row * (long)ldc + col] = acc[i][j][rg] + bv;
            }
    }
}

// ---------------- persistent LSTM scan, direct tagged exchange ----------------
// 128 blocks x 512 threads; block b owns cells [8b,8b+8) (32 gate rows).
// W_hh slice: 64 f32 VGPRs/thread. Exchange: producer lanes 0..3 store 4 tagged
// 8B words (2 x fp16 | step tag), fire-and-forget relaxed agent atomics.
// Consumers: ONE word per thread, single concurrent poll (no serialized second
// discovery), s_sleep(1) backoff between retries (cuts retry storm seen as
// ~20GB FETCH in round 0), own-block words skipped (written via LDS directly).
// Pointwise: 32 lanes of wave 0 (gate x cell), combine via intra-wave shfl.
// hs is XOR-swizzled (idx = c ^ ((c>>3)&4)) so the matvec's 16-seg reads are
// 2-way (free) instead of 4-way bank-conflicted.
__global__ __launch_bounds__(512, 1) void k_scan(
    const float* __restrict__ Whh, const float* __restrict__ gx,
    const float* __restrict__ h0, const float* __restrict__ c0,
    unsigned long long* __restrict__ hx, unsigned short* __restrict__ U) {
    __shared__ __align__(16) float hs[1024];
    __shared__ __align__(16) float gxb[32 * 32];
    __shared__ float gv[32];
    const int b = blockIdx.x, tid = threadIdx.x;
    const int lr = tid >> 4, seg = tid & 15;
    const int sw = seg & 4;               // hs half-swap swizzle for this seg

    // one-time: this thread's fixed W_hh slice -> 64 f32 registers.
    // row lr -> global gate row (lr>>3)*1024 + b*8 + (lr&7); cols u*128+seg*8+0..7
    const float* wrow = Whh + (long)((lr >> 3) * 1024 + b * 8 + (lr & 7)) * 1024;
    f32x4 wv[16];
#pragma unroll
    for (int u = 0; u < 8; ++u) {
        wv[2 * u]     = *(const f32x4*)(wrow + u * 128 + seg * 8);
        wv[2 * u + 1] = *(const f32x4*)(wrow + u * 128 + seg * 8 + 4);
    }
    // cell state: lane j (j<8) of wave 0 holds cell 8b+j
    float cst = (tid < 8) ? c0[b * 8 + tid] : 0.f;

    for (int t = 0; t < T_STEPS; ++t) {
        if ((t & 31) == 0) {   // pre-stage gates_x for steps t..t+31
            __syncthreads();   // protect gxb vs previous step's pointwise reads
            int c = tid;       // gxb[step*32 + gate*8 + cell]
            async4(gx + (long)(t + (c >> 5)) * 4096 + ((c & 31) >> 3) * 1024 + b * 8 + (c & 7), &gxb[c]);
            c = tid + 512;
            async4(gx + (long)(t + (c >> 5)) * 4096 + ((c & 31) >> 3) * 1024 + b * 8 + (c & 7), &gxb[c]);
        }
        if (t == 0) {
            int c = tid * 2;
            int idx = c ^ ((c >> 3) & 4);
            *(float2*)&hs[idx] = *(const float2*)(h0 + c);
        } else if ((tid >> 2) != b) {   // own words arrive via direct LDS write
            const unsigned long long* src = hx + (long)(t & 1) * 512 + tid;
            const unsigned tt = (unsigned)t;
            unsigned long long w = __hip_atomic_load(src, __ATOMIC_RELAXED, __HIP_MEMORY_SCOPE_AGENT);
            while ((unsigned)(w >> 32) != tt) {
                __builtin_amdgcn_s_sleep(1);   // backoff: cut coherence-point retry storm
                w = __hip_atomic_load(src, __ATOMIC_RELAXED, __HIP_MEMORY_SCOPE_AGENT);
            }
            union { unsigned u; _Float16 h[2]; } p;
            p.u = (unsigned)w;
            int c = tid * 2;
            int idx = c ^ ((c >> 3) & 4);
            hs[idx]     = (float)p.h[0];
            hs[idx + 1] = (float)p.h[1];
        }
        __syncthreads();   // hs ready; also drains gxb async loads

        // matvec: thread (lr,seg) accumulates its 64-col slice of row lr
        float acc = 0.f;
#pragma unroll
        for (int u = 0; u < 8; ++u) {
            const f32x4 ha = *(const f32x4*)&hs[u * 128 + seg * 8 + sw];
            const f32x4 hb = *(const f32x4*)&hs[u * 128 + seg * 8 + (4 ^ sw)];
            const f32x4 wa = wv[2 * u], wb = wv[2 * u + 1];
            acc += wa[0] * ha[0] + wa[1] * ha[1] + wa[2] * ha[2] + wa[3] * ha[3]
                 + wb[0] * hb[0] + wb[1] * hb[1] + wb[2] * hb[2] + wb[3] * hb[3];
        }
#pragma unroll
        for (int off = 1; off < 16; off <<= 1) acc += __shfl_xor(acc, off, 64);
        if (seg == 0) gv[lr] = acc;
        __syncthreads();

        // pointwise: 32 lanes of wave 0, one (gate,cell) each; lane = gate*8+cell
        if (tid < 32) {
            const int sl = (t & 31) * 32;
            float x = gv[tid] + gxb[sl + tid];
            const bool isg = (tid >> 3) == 2;          // lanes 16..23 = g-gate
            float y = isg ? (x + x) : x;
            float s = 1.f / (1.f + expf(-y));          // sigma(y)
            float v = isg ? (s + s - 1.f) : s;         // tanh(x) = 2*sigma(2x)-1
            const int cell = tid & 7;
            float iv = __shfl(v, cell,      64);
            float fv = __shfl(v, cell + 8,  64);
            float gg = __shfl(v, cell + 16, 64);
            float ov = __shfl(v, cell + 24, 64);
            float hn = 0.f;
            if (tid < 8) {   // lanes 0..7: one cell each
                float cn = fv * cst + iv * gg;
                cst = cn;
                hn = ov * tanhf(cn);
            }
            // pack pairs and fire the tagged stores FIRST (critical path)
            float he = __shfl(hn, (tid & 3) * 2,     64);
            float ho = __shfl(hn, (tid & 3) * 2 + 1, 64);
            if (tid < 4) {
                union { unsigned u; _Float16 h[2]; } pk;
                pk.h[0] = (_Float16)he; pk.h[1] = (_Float16)ho;
                unsigned long long word = (unsigned long long)pk.u
                                        | ((unsigned long long)(unsigned)(t + 1) << 32);
                __hip_atomic_store(&hx[(long)((t + 1) & 1) * 512 + b * 4 + tid], word,
                                   __ATOMIC_RELAXED, __HIP_MEMORY_SCOPE_AGENT);
            }
            if (tid < 8) {
                int c = b * 8 + tid;                   // own cells: straight to LDS
                hs[c ^ ((c >> 3) & 4)] = hn;
                U[(long)t * 1536 + c] = f2bf(hn);
            }
        }
        // no trailing barrier: hs/gxb overwrites happen only after the barriers
        // at the top of the next iteration (all threads passed the post-matvec
        // __syncthreads before any buffer is rewritten).
    }
}

extern "C" void kernel_launch(void* const* d_in, const int* in_sizes, int n_in,
                              void* d_out, int out_size, void* d_ws, size_t ws_size,
                              hipStream_t stream) {
    const float* h0  = (const float*)d_in[0];
    const float* c0  = (const float*)d_in[1];
    const int*   ids = (const int*)d_in[2];
    const float* emb = (const float*)d_in[3];
    const float* Wih = (const float*)d_in[4];
    const float* Whh = (const float*)d_in[5];
    const float* bih = (const float*)d_in[6];
    const float* bhh = (const float*)d_in[7];
    const float* X   = (const float*)d_in[8];
    const float* Y   = (const float*)d_in[9];
    const float* Z   = (const float*)d_in[10];
    float* out = (float*)d_out;

    char* ws = (char*)d_ws;
    size_t off = 0;
    auto take = [&](size_t bytes) -> char* {
        char* p = ws + off;
        off = (off + bytes + 511) & ~(size_t)511;
        return p;
    };
    unsigned long long* hx = (unsigned long long*)take(2 * 512 * 8);
    float* wf            = (float*)take(4096 * 4);
    float* zf            = (float*)take(32000 * 4);
    unsigned short* U    = (unsigned short*)take((size_t)512 * 1536 * 2);
    unsigned short* Wihb = (unsigned short*)take((size_t)4096 * 512 * 2);
    float* gatesx        = (float*)take((size_t)512 * 4096 * 4);
    unsigned short* Vbf  = (unsigned short*)take((size_t)32000 * 1536 * 2);
    (void)in_sizes; (void)n_in; (void)out_size; (void)ws_size;

    hipMemsetAsync(hx, 0, 2 * 512 * 8, stream);   // clear tags (poison could alias)
    // wf = W_ih[:,512:]@[h0|c0] + b_ih + b_hh ; zf = Z@[h0|c0]
    k_rowdot<<<1024, 256, 0, stream>>>(Wih, 2560, 512, h0, c0, bih, bhh, wf, 4096);
    k_rowdot<<<8000, 256, 0, stream>>>(Z, 2048, 0, h0, c0, nullptr, nullptr, zf, 32000);
    k_embs<<<512, 256, 0, stream>>>(ids, emb, U);
    k_convW<<<2048, 256, 0, stream>>>(Wih, Wihb);
    // gates_x[t][r] = emb_bf[t]·Wihb[r] + wf[r]
    k_gemm_bt<<<dim3(32, 4), 256, 0, stream>>>(U + 1024, 1536, Wihb, 512, gatesx, 4096, wf, 512);
    k_convXY<<<48000, 256, 0, stream>>>(X, Y, Vbf);
    k_scan<<<128, 512, 0, stream>>>(Whh, gatesx, h0, c0, hx, U);
    // scores = [hs|emb]·[X|Y]^T + zf
    k_gemm_bt<<<dim3(250, 4), 256, 0, stream>>>(U, 1536, Vbf, 1536, out, 32000, zf, 1536);
}